// Round 9
// baseline (501.051 us; speedup 1.0000x reference)
//
#include <hip/hip_runtime.h>

// Problem constants (MultiAttention_61340722921598)
#define BATCH 2
#define SEQ   2048
#define DMODEL 1024
#define NHEADS 16
#define HDIM   64
#define WINDOW 128
#define ROWS  (BATCH * SEQ)          // 4096
#define NBLK  512                    // persistent grid: 2 blocks/CU x 256 CUs

typedef __bf16 bf16x8 __attribute__((ext_vector_type(8)));
typedef __bf16 bf16x4 __attribute__((ext_vector_type(4)));
typedef float  f32x4  __attribute__((ext_vector_type(4)));

// async global->LDS, 16B per lane; LDS dest = wave-uniform base + lane*16
__device__ __forceinline__ void async_load16(const __bf16* g, __bf16* l) {
    __builtin_amdgcn_global_load_lds(
        (const __attribute__((address_space(1))) unsigned int*)g,
        (__attribute__((address_space(3))) unsigned int*)l, 16, 0, 0);
}

// ---------------------------------------------------------------------------
// Grid-wide barrier for the persistent kernel. All NBLK blocks are co-resident
// by construction (LDS 55.3KB -> exactly 2 blocks/CU; launch_bounds(256,2)).
// __threadfence_system flushes/invalidates through the non-coherent per-XCD
// L2s on both sides; atomics are device-scope (verified m20).
// ---------------------------------------------------------------------------
__device__ __forceinline__ void grid_barrier(unsigned* cnt, unsigned* gen)
{
    __syncthreads();                 // all block stores drained to L2
    __threadfence_system();          // writeback: our data device-visible
    if (threadIdx.x == 0) {
        unsigned g = atomicAdd(gen, 0u);          // atomic load
        if (atomicAdd(cnt, 1u) == NBLK - 1) {
            atomicExch(cnt, 0u);
            atomicAdd(gen, 1u);                   // release generation
        } else {
            while (atomicAdd(gen, 0u) == g) __builtin_amdgcn_s_sleep(2);
        }
    }
    __syncthreads();
    __threadfence_system();          // invalidate before reading others' data
}

// ---------------------------------------------------------------------------
// bf16 MFMA GEMM tile body (r8-verified): C[m][n] = sum_k A[m][k]*B[n][k].
// TM=128 x TN=64 tile, BK=128 (4 x 32-halves, XOR chunk swizzle - 0 conflicts
// measured r4-r8). 4 waves, 4x1 layout. LDS passed in (shared with attn).
// Modes: 0=Q (RoPE+0.125, bf16), 1=K (RoPE, bf16), 2=V (bf16), 3=fp32+bias.
// A/B-frag: elem[row=lane&15][k=(lane>>4)*8+j]; C/D: col=lane&15,
// row=(lane>>4)*4+reg (verified m89, rounds 2-8).
// ---------------------------------------------------------------------------
__device__ __forceinline__ void gemm_tile(
    __bf16* Asb, __bf16* Bsb,
    const __bf16* __restrict__ A, const __bf16* __restrict__ B,
    void* __restrict__ Cout, const float* __restrict__ bias,
    const float* __restrict__ ct, const float* __restrict__ st,
    int mode, int N, int K, int m0, int n0)
{
    const int tid  = threadIdx.x;
    const int lane = tid & 63;
    const int wv   = tid >> 6;
    const int wrow = wv * 32;            // TM/4

    const int srow = lane >> 2;
    const int schk = (lane & 3) ^ ((lane >> 3) & 3);
    const int arbase = wv * 32;
    const int brbase = wv * 16;

    const __bf16* gA0 = A + (size_t)(m0 + arbase + srow) * K + 8 * schk;
    const __bf16* gA1 = gA0 + (size_t)16 * K;
    const __bf16* gB0 = B + (size_t)(n0 + brbase + srow) * K + 8 * schk;

    const int frow = lane & 15;
    const int fsw  = 8 * ((lane >> 4) ^ ((frow >> 1) & 3));

    f32x4 acc[2][4];
#pragma unroll
    for (int i = 0; i < 2; ++i)
#pragma unroll
        for (int j = 0; j < 4; ++j) {
            acc[i][j][0] = 0.f; acc[i][j][1] = 0.f;
            acc[i][j][2] = 0.f; acc[i][j][3] = 0.f;
        }

    for (int k0 = 0; k0 < K; k0 += 128) {
        __syncthreads();                 // prior LDS reads complete
#pragma unroll
        for (int h = 0; h < 4; ++h) {
            async_load16(gA0 + k0 + 32 * h, Asb + h * (128 * 32) + arbase * 32);
            async_load16(gA1 + k0 + 32 * h, Asb + h * (128 * 32) + (arbase + 16) * 32);
            async_load16(gB0 + k0 + 32 * h, Bsb + h * (64 * 32) + brbase * 32);
        }
        __syncthreads();                 // drains vmcnt: staging visible

#pragma unroll
        for (int h = 0; h < 4; ++h) {
            const __bf16* Ah = Asb + h * (128 * 32);
            const __bf16* Bh = Bsb + h * (64 * 32);
            bf16x8 afr[2], bfr[4];
#pragma unroll
            for (int i = 0; i < 2; ++i)
                afr[i] = *(const bf16x8*)(Ah + (wrow + 16 * i + frow) * 32 + fsw);
#pragma unroll
            for (int j = 0; j < 4; ++j)
                bfr[j] = *(const bf16x8*)(Bh + (16 * j + frow) * 32 + fsw);
#pragma unroll
            for (int i = 0; i < 2; ++i)
#pragma unroll
                for (int j = 0; j < 4; ++j)
                    acc[i][j] = __builtin_amdgcn_mfma_f32_16x16x32_bf16(
                        afr[i], bfr[j], acc[i][j], 0, 0, 0);
        }
    }

#pragma unroll
    for (int i = 0; i < 2; ++i) {
#pragma unroll
        for (int r = 0; r < 4; ++r) {
            int row = m0 + wrow + i * 16 + (lane >> 4) * 4 + r;
            if (mode <= 1) {
                int t = row & (SEQ - 1);
#pragma unroll
                for (int j = 0; j < 2; ++j) {
                    int dd = j * 16 + (lane & 15);
                    float c = ct[t * 32 + dd];
                    float s = st[t * 32 + dd];
                    float v0 = acc[i][j][r], v1 = acc[i][j + 2][r];
                    float n0v = v0 * c - v1 * s;
                    float n1v = v1 * c + v0 * s;
                    if (mode == 0) { n0v *= 0.125f; n1v *= 0.125f; }
                    acc[i][j][r] = n0v; acc[i][j + 2][r] = n1v;
                }
            }
#pragma unroll
            for (int j = 0; j < 4; ++j) {
                int col = n0 + j * 16 + (lane & 15);
                float v = acc[i][j][r];
                if (mode == 3)
                    ((float*)Cout)[(size_t)row * N + col] = v + bias[col];
                else
                    ((__bf16*)Cout)[(size_t)row * N + col] = (__bf16)v;
            }
        }
    }
}

// ---------------------------------------------------------------------------
// MFMA sliding-window attention unit (verified rounds 3-8), LDS passed in.
// u in [0,1024): q-tile (u&31), head (u>>5)&15, batch (u>>9).
// ---------------------------------------------------------------------------
#define QTILE 64
#define KPAD  72
#define VPAD  216
#define PPAD  168

__device__ __forceinline__ void attn_unit(
    char* sm, int u,
    const __bf16* __restrict__ Qb, const __bf16* __restrict__ Kb,
    const __bf16* __restrict__ Vb, __bf16* __restrict__ Abf)
{
    __bf16* KsPs = (__bf16*)sm;          // 27648 B; Ks then reused as Ps
    __bf16* Vt   = KsPs + 192 * KPAD;    // 27648 B (total 55296)

    const int tid  = threadIdx.x;
    const int lane = tid & 63;
    const int wv   = tid >> 6;
    const int q0   = (u & 31) * QTILE;
    const int h    = (u >> 5) & 15;
    const int bb   = u >> 9;
    const int jbase = q0 - 128;
    const size_t hoff = (size_t)h * HDIM;
    const int nloc  = lane & 15;
    const int mbase = (lane >> 4) * 4;
    const int fk    = (lane >> 4) * 8;

    const __bf16* Kg = Kb + (size_t)(bb * SEQ) * DMODEL + hoff;
    const __bf16* Vg = Vb + (size_t)(bb * SEQ) * DMODEL + hoff;

    __syncthreads();                     // prior users of sm done

    // ---- stage Ks (natural) + Vt (transposed)
#pragma unroll
    for (int it = 0; it < 6; ++it) {
        int idx = tid + it * 256;
        int jt = idx >> 3;
        int dq = (idx & 7) * 8;
        int jg = jbase + jt;
        int jc = jg < 0 ? 0 : jg;
        bf16x8 kv = *(const bf16x8*)(Kg + (size_t)jc * DMODEL + dq);
        bf16x8 vv = *(const bf16x8*)(Vg + (size_t)jc * DMODEL + dq);
        *(bf16x8*)(KsPs + jt * KPAD + dq) = kv;
#pragma unroll
        for (int e = 0; e < 8; ++e) Vt[(dq + e) * VPAD + jt] = vv[e];
    }
#pragma unroll
    for (int it = 0; it < 4; ++it) {
        int idx = tid + it * 256;
        int d = idx >> 4, c = idx & 15;
        Vt[d * VPAD + 192 + c] = (__bf16)0.0f;
    }
    __syncthreads();

    const __bf16* Qg = Qb + (size_t)(bb * SEQ + q0 + 16 * wv + nloc) * DMODEL + hoff + fk;
    bf16x8 qfr0 = *(const bf16x8*)(Qg);
    bf16x8 qfr1 = *(const bf16x8*)(Qg + 32);

    f32x4 s[9];
#pragma unroll
    for (int c = 0; c < 9; ++c) {
        const __bf16* kp = KsPs + (size_t)(16 * (wv + c) + nloc) * KPAD + fk;
        bf16x8 k0 = *(const bf16x8*)kp;
        bf16x8 k1 = *(const bf16x8*)(kp + 32);
        f32x4 z; z[0] = 0.f; z[1] = 0.f; z[2] = 0.f; z[3] = 0.f;
        z = __builtin_amdgcn_mfma_f32_16x16x32_bf16(qfr0, k0, z, 0, 0, 0);
        z = __builtin_amdgcn_mfma_f32_16x16x32_bf16(qfr1, k1, z, 0, 0, 0);
        s[c] = z;
    }
    __syncthreads();   // all waves done reading Ks; safe to alias with Ps

    float inv_row[4];
#pragma unroll
    for (int r = 0; r < 4; ++r) {
        int rl = 16 * wv + mbase + r;
        float mx = -INFINITY;
#pragma unroll
        for (int c = 0; c < 9; ++c) {
            int jt = 16 * (wv + c) + nloc;
            bool valid = (jt >= rl + 1) && (jt <= rl + 128) && (jbase + jt >= 0);
            float sv = valid ? s[c][r] : -INFINITY;
            s[c][r] = sv;
            mx = fmaxf(mx, sv);
        }
#pragma unroll
        for (int off = 8; off; off >>= 1) mx = fmaxf(mx, __shfl_xor(mx, off));
        float sum = 0.f;
#pragma unroll
        for (int c = 0; c < 9; ++c) {
            float p = __expf(s[c][r] - mx);
            s[c][r] = p;
            sum += p;
        }
#pragma unroll
        for (int off = 8; off; off >>= 1) sum += __shfl_xor(sum, off);
        inv_row[r] = 1.0f / sum;
    }

    __bf16* myP = KsPs + (size_t)wv * 16 * PPAD;
#pragma unroll
    for (int c = 0; c < 9; ++c)
#pragma unroll
        for (int r = 0; r < 4; ++r)
            myP[(mbase + r) * PPAD + 16 * c + nloc] = (__bf16)(s[c][r] * inv_row[r]);
#pragma unroll
    for (int r = 0; r < 4; ++r)
        myP[(mbase + r) * PPAD + 144 + nloc] = (__bf16)0.0f;

    asm volatile("" ::: "memory");
    __builtin_amdgcn_s_waitcnt(0);    // wave-local LDS write->read ordering

    f32x4 o[4];
#pragma unroll
    for (int j = 0; j < 4; ++j) { o[j][0] = 0.f; o[j][1] = 0.f; o[j][2] = 0.f; o[j][3] = 0.f; }
#pragma unroll
    for (int stp = 0; stp < 5; ++stp) {
        bf16x8 pf = *(const bf16x8*)(myP + nloc * PPAD + 32 * stp + fk);
#pragma unroll
        for (int j = 0; j < 4; ++j) {
            bf16x8 vf = *(const bf16x8*)(Vt + (size_t)(16 * j + nloc) * VPAD
                                         + 16 * wv + 32 * stp + fk);
            o[j] = __builtin_amdgcn_mfma_f32_16x16x32_bf16(pf, vf, o[j], 0, 0, 0);
        }
    }

    __bf16* Og = Abf + (size_t)(bb * SEQ + q0 + 16 * wv) * DMODEL + hoff;
#pragma unroll
    for (int j = 0; j < 4; ++j)
#pragma unroll
        for (int r = 0; r < 4; ++r)
            Og[(size_t)(mbase + r) * DMODEL + 16 * j + nloc] = (__bf16)o[j][r];
}

// ---------------------------------------------------------------------------
// ONE persistent kernel: convert+rope-table | barrier | QKV (3 tiles/block)
// | barrier | attention (2 units/block) | barrier | out-proj (1 tile/block).
// 512 blocks = 2/CU (LDS-bound occupancy = grid) -> co-resident, manual grid
// barrier valid. x/y tile map keeps the 16 blocks sharing an X-row-stripe on
// one XCD (r7-verified: FETCH 83->39 MB).
// ---------------------------------------------------------------------------
__global__ __launch_bounds__(256, 2) void fused_all(
    const float* __restrict__ X,
    const float* __restrict__ Wq, const float* __restrict__ Wk,
    const float* __restrict__ Wv, const float* __restrict__ Wo,
    const float* __restrict__ bo, float* __restrict__ out,
    __bf16* __restrict__ Xbf, __bf16* __restrict__ Wbf,
    __bf16* __restrict__ Qb, __bf16* __restrict__ Kb, __bf16* __restrict__ Vb,
    __bf16* __restrict__ Abf, float* __restrict__ ct, float* __restrict__ st,
    unsigned* bar)
{
    __shared__ __align__(16) char smem[55296];
    __bf16* As = (__bf16*)smem;              // 4*128*32 bf16 = 32768 B
    __bf16* Bs = As + 4 * 128 * 32;          // 4*64*32 bf16  = 16384 B
    unsigned* cnt = bar;
    unsigned* gen = bar + 1;

    const int b   = blockIdx.x;
    const int tid = threadIdx.x;

    // ---- S0: fp32->bf16 convert (X + 4 weights) + RoPE table
    {
        const int XN = ROWS * DMODEL / 4;
        const int WN = DMODEL * DMODEL / 4;
        const int TOT = XN + 4 * WN;                    // 2,097,152
        const int LIM = TOT + SEQ * 32;
        for (int base = 0; base < LIM; base += NBLK * 256) {
            int idx = base + b * 256 + tid;
            if (idx < TOT) {
                const float* src;
                __bf16* dst;
                if (idx < XN) {
                    src = X + (size_t)idx * 4;
                    dst = Xbf + (size_t)idx * 4;
                } else {
                    int rel = idx - XN;
                    int w = rel / WN;
                    int off = rel - w * WN;
                    const float* Wp = (w == 0) ? Wq : (w == 1) ? Wk
                                    : (w == 2) ? Wv : Wo;
                    src = Wp + (size_t)off * 4;
                    dst = Wbf + (size_t)rel * 4;
                }
                float4 v = *(const float4*)src;
                bf16x4 o;
                o[0] = (__bf16)v.x; o[1] = (__bf16)v.y;
                o[2] = (__bf16)v.z; o[3] = (__bf16)v.w;
                *(bf16x4*)dst = o;
            } else if (idx < LIM) {
                int k = idx - TOT;
                int t = k >> 5, d = k & 31;
                float ang = (float)t * expf(-(float)d * 0.28782313662425572f);
                float s, c;
                sincosf(ang, &s, &c);
                ct[k] = c; st[k] = s;
            }
        }
    }
    grid_barrier(cnt, gen);

    // ---- S1: QKV projections, fused RoPE (+Q scale). 3 tiles per block.
    {
        const int x = (b >> 3) & 15;            // 16 n-tiles of 64
        const int y = 4 * (b & 7) + (b >> 7);   // 32 m-tiles of 128, XCD-local
        for (int z = 0; z < 3; ++z) {
            __bf16* C = (z == 0) ? Qb : (z == 1) ? Kb : Vb;
            gemm_tile(As, Bs, Xbf, Wbf + (size_t)z * DMODEL * DMODEL,
                      C, nullptr, ct, st, z, DMODEL, DMODEL, y * 128, x * 64);
        }
    }
    grid_barrier(cnt, gen);

    // ---- S2: sliding-window attention, 2 units per block
    attn_unit(smem, b,        Qb, Kb, Vb, Abf);
    attn_unit(smem, b + NBLK, Qb, Kb, Vb, Abf);
    grid_barrier(cnt, gen);

    // ---- S3: output projection + bias, 1 tile per block
    {
        const int x = (b >> 3) & 15;
        const int y = 4 * (b & 7) + (b >> 7);
        gemm_tile(As, Bs, Abf, Wbf + 3ull * DMODEL * DMODEL,
                  out, bo, nullptr, nullptr, 3, DMODEL, DMODEL, y * 128, x * 64);
    }
}

// ---------------------------------------------------------------------------
extern "C" void kernel_launch(void* const* d_in, const int* in_sizes, int n_in,
                              void* d_out, int out_size, void* d_ws, size_t ws_size,
                              hipStream_t stream)
{
    const float* X  = (const float*)d_in[0];
    const float* Wq = (const float*)d_in[1];
    const float* Wk = (const float*)d_in[2];
    const float* Wv = (const float*)d_in[3];
    const float* Wo = (const float*)d_in[4];
    const float* bo = (const float*)d_in[5];
    float* out = (float*)d_out;

    const size_t MB = 1ull << 20;
    __bf16* Xbf = (__bf16*)d_ws;                         // 8 MB
    __bf16* Wbf = (__bf16*)((char*)d_ws + 8 * MB);       // 8 MB (Wq|Wk|Wv|Wo)
    __bf16* Qb  = (__bf16*)((char*)d_ws + 16 * MB);      // 8 MB
    __bf16* Kb  = (__bf16*)((char*)d_ws + 24 * MB);      // 8 MB
    __bf16* Vb  = (__bf16*)((char*)d_ws + 32 * MB);      // 8 MB
    float*  ctab = (float*)((char*)d_ws + 40 * MB);      // 256 KB
    float*  stab = (float*)((char*)d_ws + 41 * MB);      // 256 KB
    __bf16* Abf = (__bf16*)((char*)d_ws + 42 * MB);      // 8 MB (no aliasing)
    unsigned* bar = (unsigned*)((char*)d_ws + 50 * MB);  // barrier state

    // zero the grid-barrier words (d_ws is re-poisoned 0xAA before each call)
    hipMemsetAsync(bar, 0, 64, stream);

    fused_all<<<NBLK, 256, 0, stream>>>(
        X, Wq, Wk, Wv, Wo, bo, out,
        Xbf, Wbf, Qb, Kb, Vb, Abf, ctab, stab, bar);
}

// Round 10
// 163.542 us; speedup vs baseline: 3.0637x; 3.0637x over previous
//
#include <hip/hip_runtime.h>

// Problem constants (MultiAttention_61340722921598)
#define BATCH 2
#define SEQ   2048
#define DMODEL 1024
#define NHEADS 16
#define HDIM   64
#define WINDOW 128
#define ROWS  (BATCH * SEQ)          // 4096

typedef __bf16 bf16x8 __attribute__((ext_vector_type(8)));
typedef __bf16 bf16x4 __attribute__((ext_vector_type(4)));
typedef float  f32x4  __attribute__((ext_vector_type(4)));

// async global->LDS, 16B per lane; LDS dest = wave-uniform base + lane*16
__device__ __forceinline__ void async_load16(const __bf16* g, __bf16* l) {
    __builtin_amdgcn_global_load_lds(
        (const __attribute__((address_space(1))) unsigned int*)g,
        (__attribute__((address_space(3))) unsigned int*)l, 16, 0, 0);
}

// ---------------------------------------------------------------------------
// fp32 -> bf16 conversion of X and the 4 weights; tail range computes the
// RoPE cos/sin table (exact libm sincosf, matching the fp32 reference).
// ---------------------------------------------------------------------------
__global__ __launch_bounds__(256) void convert_bf16(
    const float* __restrict__ X,
    const float* __restrict__ Wq, const float* __restrict__ Wk,
    const float* __restrict__ Wv, const float* __restrict__ Wo,
    __bf16* __restrict__ Xbf, __bf16* __restrict__ Wbf,
    float* __restrict__ ct, float* __restrict__ st)
{
    const int XN = ROWS * DMODEL / 4;     // 1,048,576 groups
    const int WN = DMODEL * DMODEL / 4;   // 262,144 per W
    const int TOT = XN + 4 * WN;          // 2,097,152
    int idx = blockIdx.x * blockDim.x + threadIdx.x;

    if (idx < TOT) {
        const float* src;
        __bf16* dst;
        if (idx < XN) {
            src = X + (size_t)idx * 4;
            dst = Xbf + (size_t)idx * 4;
        } else {
            int rel = idx - XN;
            int w = rel / WN;
            int off = rel - w * WN;
            const float* Wp = (w == 0) ? Wq : (w == 1) ? Wk : (w == 2) ? Wv : Wo;
            src = Wp + (size_t)off * 4;
            dst = Wbf + (size_t)rel * 4;
        }
        float4 v = *(const float4*)src;
        bf16x4 o;
        o[0] = (__bf16)v.x; o[1] = (__bf16)v.y; o[2] = (__bf16)v.z; o[3] = (__bf16)v.w;
        *(bf16x4*)dst = o;
    } else if (idx < TOT + SEQ * 32) {
        int k = idx - TOT;
        int t = k >> 5, d = k & 31;
        float ang = (float)t * expf(-(float)d * 0.28782313662425572f); // ln(1e4)/32
        float s, c;
        sincosf(ang, &s, &c);
        ct[k] = c; st[k] = s;
    }
}

// ---------------------------------------------------------------------------
// bf16 MFMA GEMM: C[m][n] = sum_k A[m][k] * B[n][k]. BK=128 (4 x 32-halves,
// XOR chunk swizzle per the r4-verified pattern: LDS row r slot s holds
// global chunk s^((r>>1)&3) via source-address permutation; 0 conflicts
// measured r4-r8). 256 threads = 4 waves.
//   TN=128 -> 2x2 wave layout: wave = 64x64 outputs, 8 ds_read_b128 per
//             16 MFMA (0.5/MFMA, m97 ratio). LDS 64 KB, 2 blocks/CU.
//   TN=64  -> 4x1 wave layout (r8-verified, used for out-proj).
// Epilogue modes: 0=Q (RoPE+0.125, bf16), 1=K (RoPE, bf16), 2=V (bf16),
// 3=fp32+bias. wcol is a multiple of 64 in both layouts -> RoPE pairs
// (d, d+32) stay in one wave as (acc[i][j], acc[i][j+2]), d=j*16+(lane&15).
// A/B-frag: elem[row=lane&15][k=(lane>>4)*8+j]; C/D: col=lane&15,
// row=(lane>>4)*4+reg (verified m89, rounds 2-8).
// ---------------------------------------------------------------------------
template<int TM, int TN>
__device__ __forceinline__ void gemm_mfma_body(
    const __bf16* __restrict__ A, const __bf16* __restrict__ B,
    void* __restrict__ Cout, const float* __restrict__ bias,
    const float* __restrict__ ct, const float* __restrict__ st,
    int mode, int N, int K, int m0, int n0)
{
    constexpr bool SQ = (TN == 128);          // 2x2 wave layout
    constexpr int NI = SQ ? 4 : (TM / 64);    // 16-row i-tiles per wave
    constexpr int NAC = TM / 64;              // A staging calls per wave/half
    constexpr int NBC = TN / 64;              // B staging calls per wave/half
    __shared__ __bf16 As[4][TM * 32];
    __shared__ __bf16 Bs[4][TN * 32];

    const int tid  = threadIdx.x;
    const int lane = tid & 63;
    const int wv   = tid >> 6;
    const int wrow = SQ ? (wv >> 1) * 64 : wv * (TM / 4);
    const int wcol = SQ ? (wv & 1) * 64 : 0;

    // staging map (per 16-row call): lane -> row lane>>2, slot lane&3,
    // source chunk (lane&3)^((lane>>3)&3); row-base-invariant (base % 16 == 0)
    const int srow = lane >> 2;
    const int schk = (lane & 3) ^ ((lane >> 3) & 3);
    const int arbase = wv * (TM / 4);
    const int brbase = wv * (TN / 4);

    const __bf16* gA0 = A + (size_t)(m0 + arbase + srow) * K + 8 * schk;
    const __bf16* gA1 = gA0 + (size_t)16 * K;
    const __bf16* gB0 = B + (size_t)(n0 + brbase + srow) * K + 8 * schk;
    const __bf16* gB1 = gB0 + (size_t)16 * K;

    // fragment read map: row frow, global chunk lane>>4 at swizzled slot
    const int frow = lane & 15;
    const int fsw  = 8 * ((lane >> 4) ^ ((frow >> 1) & 3));

    f32x4 acc[NI][4];
#pragma unroll
    for (int i = 0; i < NI; ++i)
#pragma unroll
        for (int j = 0; j < 4; ++j) {
            acc[i][j][0] = 0.f; acc[i][j][1] = 0.f;
            acc[i][j][2] = 0.f; acc[i][j][3] = 0.f;
        }

    for (int k0 = 0; k0 < K; k0 += 128) {
        __syncthreads();                 // prior iter's LDS reads complete
#pragma unroll
        for (int h = 0; h < 4; ++h) {
            async_load16(gA0 + k0 + 32 * h, As[h] + arbase * 32);
            if (NAC == 2)
                async_load16(gA1 + k0 + 32 * h, As[h] + (arbase + 16) * 32);
            async_load16(gB0 + k0 + 32 * h, Bs[h] + brbase * 32);
            if (NBC == 2)
                async_load16(gB1 + k0 + 32 * h, Bs[h] + (brbase + 16) * 32);
        }
        __syncthreads();                 // drains vmcnt: staging visible

#pragma unroll
        for (int h = 0; h < 4; ++h) {
            bf16x8 afr[NI], bfr[4];
#pragma unroll
            for (int i = 0; i < NI; ++i)
                afr[i] = *(const bf16x8*)(As[h] + (wrow + 16 * i + frow) * 32 + fsw);
#pragma unroll
            for (int j = 0; j < 4; ++j)
                bfr[j] = *(const bf16x8*)(Bs[h] + (wcol + 16 * j + frow) * 32 + fsw);
#pragma unroll
            for (int i = 0; i < NI; ++i)
#pragma unroll
                for (int j = 0; j < 4; ++j)
                    acc[i][j] = __builtin_amdgcn_mfma_f32_16x16x32_bf16(
                        afr[i], bfr[j], acc[i][j], 0, 0, 0);
        }
    }

#pragma unroll
    for (int i = 0; i < NI; ++i) {
#pragma unroll
        for (int r = 0; r < 4; ++r) {
            int row = m0 + wrow + i * 16 + (lane >> 4) * 4 + r;
            if (mode <= 1) {
                // RoPE: pairs (d, d+32) in (acc[i][j], acc[i][j+2]), d=j*16+(lane&15)<32
                int t = row & (SEQ - 1);
#pragma unroll
                for (int j = 0; j < 2; ++j) {
                    int dd = j * 16 + (lane & 15);
                    float c = ct[t * 32 + dd];
                    float s = st[t * 32 + dd];
                    float v0 = acc[i][j][r], v1 = acc[i][j + 2][r];
                    float n0v = v0 * c - v1 * s;
                    float n1v = v1 * c + v0 * s;
                    if (mode == 0) { n0v *= 0.125f; n1v *= 0.125f; }
                    acc[i][j][r] = n0v; acc[i][j + 2][r] = n1v;
                }
            }
#pragma unroll
            for (int j = 0; j < 4; ++j) {
                int col = n0 + wcol + j * 16 + (lane & 15);
                float v = acc[i][j][r];
                if (mode == 3)
                    ((float*)Cout)[(size_t)row * N + col] = v + bias[col];
                else
                    ((__bf16*)Cout)[(size_t)row * N + col] = (__bf16)v;
            }
        }
    }
}

// XCD-locality swizzle (verified r7/r8): id = bx + GX*by, XCD = id&7
// (round-robin dispatch). Each XCD gets GY/8 y-stripes so the GX blocks
// sharing one A-row-tile sit on ONE XCD; z-stride GX*GY % 8 == 0 keeps the
// same (x,y) on the same XCD across z.
template<int GX, int GY>
__device__ __forceinline__ void xcd_swizzle(int& xb, int& yb)
{
    int id = blockIdx.x + GX * blockIdx.y;
    int q  = id & 7;
    int s  = id >> 3;
    xb = s % GX;
    yb = (GY / 8) * q + s / GX;
}

__global__ __launch_bounds__(256) void gemm_qkv_bf(
    const __bf16* __restrict__ X, const __bf16* __restrict__ Wbf,
    __bf16* __restrict__ Qb, __bf16* __restrict__ Kb, __bf16* __restrict__ Vb,
    const float* __restrict__ ct, const float* __restrict__ st)
{
    const int z = blockIdx.z;
    const __bf16* W = Wbf + (size_t)z * (DMODEL * DMODEL);
    __bf16* C = (z == 0) ? Qb : (z == 1) ? Kb : Vb;
    int xb, yb;
    xcd_swizzle<8, 32>(xb, yb);
    gemm_mfma_body<128, 128>(X, W, C, nullptr, ct, st, z, DMODEL, DMODEL,
                             yb * 128, xb * 128);
}

__global__ __launch_bounds__(256) void gemm_out_bf(
    const __bf16* __restrict__ Abf, const __bf16* __restrict__ Wo,
    const float* __restrict__ bias, float* __restrict__ out)
{
    int xb, yb;
    xcd_swizzle<16, 64>(xb, yb);
    gemm_mfma_body<64, 64>(Abf, Wo, out, bias, nullptr, nullptr, 3,
                           DMODEL, DMODEL, yb * 64, xb * 64);
}

// ---------------------------------------------------------------------------
// MFMA sliding-window attention (verified rounds 3-8). One 256-thread block
// per (b, h, 64 q-rows); wave w owns q-rows 16w..16w+15.
// ---------------------------------------------------------------------------
#define QTILE 64
#define KPAD  72    // Ks row (bf16): 36 words/row -> 8 distinct bank offsets
#define VPAD  216   // Vt row: 108 words -> 8 distinct offsets
#define PPAD  168   // Ps row: 84 words -> 8 distinct offsets

__global__ __launch_bounds__(256) void attn_mfma(
    const __bf16* __restrict__ Qb, const __bf16* __restrict__ Kb,
    const __bf16* __restrict__ Vb, __bf16* __restrict__ Abf)
{
    __shared__ __bf16 KsPs[192 * KPAD];  // 27648 B; Ks, then reused as Ps
    __shared__ __bf16 Vt[64 * VPAD];     // 27648 B  (total 55296 B)

    const int tid  = threadIdx.x;
    const int lane = tid & 63;
    const int wv   = tid >> 6;
    const int q0   = blockIdx.x * QTILE;
    const int h    = blockIdx.y;
    const int b    = blockIdx.z;
    const int jbase = q0 - 128;
    const size_t hoff = (size_t)h * HDIM;
    const int nloc  = lane & 15;
    const int mbase = (lane >> 4) * 4;
    const int fk    = (lane >> 4) * 8;

    const __bf16* Kg = Kb + (size_t)(b * SEQ) * DMODEL + hoff;
    const __bf16* Vg = Vb + (size_t)(b * SEQ) * DMODEL + hoff;

    // ---- stage Ks (natural) + Vt (transposed)
#pragma unroll
    for (int it = 0; it < 6; ++it) {
        int idx = tid + it * 256;          // 0..1535
        int jt = idx >> 3;                 // 0..191
        int dq = (idx & 7) * 8;
        int jg = jbase + jt;
        int jc = jg < 0 ? 0 : jg;          // clamp; masked via p=0 later
        bf16x8 kv = *(const bf16x8*)(Kg + (size_t)jc * DMODEL + dq);
        bf16x8 vv = *(const bf16x8*)(Vg + (size_t)jc * DMODEL + dq);
        *(bf16x8*)(KsPs + jt * KPAD + dq) = kv;
#pragma unroll
        for (int e = 0; e < 8; ++e) Vt[(dq + e) * VPAD + jt] = vv[e];
    }
    // zero Vt cols [192,208) (read by PV k-steps; must not be garbage)
#pragma unroll
    for (int it = 0; it < 4; ++it) {
        int idx = tid + it * 256;          // 0..1023
        int d = idx >> 4, c = idx & 15;
        Vt[d * VPAD + 192 + c] = (__bf16)0.0f;
    }
    __syncthreads();

    // ---- Q A-frags direct from global
    const __bf16* Qg = Qb + (size_t)(b * SEQ + q0 + 16 * wv + nloc) * DMODEL + hoff + fk;
    bf16x8 qfr0 = *(const bf16x8*)(Qg);
    bf16x8 qfr1 = *(const bf16x8*)(Qg + 32);

    // ---- S = Q K^T over 9 column tiles
    f32x4 s[9];
#pragma unroll
    for (int c = 0; c < 9; ++c) {
        const __bf16* kp = KsPs + (size_t)(16 * (wv + c) + nloc) * KPAD + fk;
        bf16x8 k0 = *(const bf16x8*)kp;
        bf16x8 k1 = *(const bf16x8*)(kp + 32);
        f32x4 z; z[0] = 0.f; z[1] = 0.f; z[2] = 0.f; z[3] = 0.f;
        z = __builtin_amdgcn_mfma_f32_16x16x32_bf16(qfr0, k0, z, 0, 0, 0);
        z = __builtin_amdgcn_mfma_f32_16x16x32_bf16(qfr1, k1, z, 0, 0, 0);
        s[c] = z;
    }
    __syncthreads();   // all waves done reading Ks; safe to alias with Ps

    // ---- mask + softmax (registers only); write normalized P (bf16)
    float inv_row[4];
#pragma unroll
    for (int r = 0; r < 4; ++r) {
        int rl = 16 * wv + mbase + r;
        float mx = -INFINITY;
#pragma unroll
        for (int c = 0; c < 9; ++c) {
            int jt = 16 * (wv + c) + nloc;
            bool valid = (jt >= rl + 1) && (jt <= rl + 128) && (jbase + jt >= 0);
            float sv = valid ? s[c][r] : -INFINITY;
            s[c][r] = sv;
            mx = fmaxf(mx, sv);
        }
#pragma unroll
        for (int off = 8; off; off >>= 1) mx = fmaxf(mx, __shfl_xor(mx, off));
        float sum = 0.f;
#pragma unroll
        for (int c = 0; c < 9; ++c) {
            float p = __expf(s[c][r] - mx);
            s[c][r] = p;
            sum += p;
        }
#pragma unroll
        for (int off = 8; off; off >>= 1) sum += __shfl_xor(sum, off);
        inv_row[r] = 1.0f / sum;
    }

    __bf16* myP = KsPs + (size_t)wv * 16 * PPAD;
#pragma unroll
    for (int c = 0; c < 9; ++c)
#pragma unroll
        for (int r = 0; r < 4; ++r)
            myP[(mbase + r) * PPAD + 16 * c + nloc] = (__bf16)(s[c][r] * inv_row[r]);
#pragma unroll
    for (int r = 0; r < 4; ++r)       // zero P cols [144,160)
        myP[(mbase + r) * PPAD + 144 + nloc] = (__bf16)0.0f;

    asm volatile("" ::: "memory");
    __builtin_amdgcn_s_waitcnt(0);    // wave-local LDS write->read ordering

    // ---- O = P V  (5 k-steps of 32 keys, 4 d-tiles)
    f32x4 o[4];
#pragma unroll
    for (int j = 0; j < 4; ++j) { o[j][0] = 0.f; o[j][1] = 0.f; o[j][2] = 0.f; o[j][3] = 0.f; }
#pragma unroll
    for (int stp = 0; stp < 5; ++stp) {
        bf16x8 pf = *(const bf16x8*)(myP + nloc * PPAD + 32 * stp + fk);
#pragma unroll
        for (int j = 0; j < 4; ++j) {
            bf16x8 vf = *(const bf16x8*)(Vt + (size_t)(16 * j + nloc) * VPAD
                                         + 16 * wv + 32 * stp + fk);
            o[j] = __builtin_amdgcn_mfma_f32_16x16x32_bf16(pf, vf, o[j], 0, 0, 0);
        }
    }

    // ---- epilogue: C-layout -> global bf16
    __bf16* Og = Abf + (size_t)(b * SEQ + q0 + 16 * wv) * DMODEL + hoff;
#pragma unroll
    for (int j = 0; j < 4; ++j)
#pragma unroll
        for (int r = 0; r < 4; ++r)
            Og[(size_t)(mbase + r) * DMODEL + 16 * j + nloc] = (__bf16)o[j][r];
}

// ---------------------------------------------------------------------------
extern "C" void kernel_launch(void* const* d_in, const int* in_sizes, int n_in,
                              void* d_out, int out_size, void* d_ws, size_t ws_size,
                              hipStream_t stream)
{
    const float* X  = (const float*)d_in[0];
    const float* Wq = (const float*)d_in[1];
    const float* Wk = (const float*)d_in[2];
    const float* Wv = (const float*)d_in[3];
    const float* Wo = (const float*)d_in[4];
    const float* bo = (const float*)d_in[5];
    float* out = (float*)d_out;

    const size_t MB = 1ull << 20;
    __bf16* Xbf = (__bf16*)d_ws;                        // 8 MB; reused as Abf
    __bf16* Wbf = (__bf16*)((char*)d_ws + 8 * MB);      // 8 MB (Wq|Wk|Wv|Wo)
    __bf16* Qb  = (__bf16*)((char*)d_ws + 16 * MB);     // 8 MB
    __bf16* Kb  = (__bf16*)((char*)d_ws + 24 * MB);     // 8 MB
    __bf16* Vb  = (__bf16*)((char*)d_ws + 32 * MB);     // 8 MB
    float*  ctab = (float*)((char*)d_ws + 40 * MB);     // 256 KB
    float*  stab = (float*)((char*)d_ws + 41 * MB);     // 256 KB
    __bf16* Abf = Xbf;   // X dead after QKV projection

    // 1. fp32 -> bf16 conversion + RoPE table (fused)
    {
        int total = (ROWS * DMODEL + 4 * DMODEL * DMODEL) / 4 + SEQ * 32;
        convert_bf16<<<(total + 255) / 256, 256, 0, stream>>>(
            X, Wq, Wk, Wv, Wo, Xbf, Wbf, ctab, stab);
    }
    // 2. QKV projections with fused RoPE (+Q scale), bf16 out; 128x128 tiles
    {
        dim3 grid(DMODEL / 128, ROWS / 128, 3);
        gemm_qkv_bf<<<grid, 256, 0, stream>>>(Xbf, Wbf, Qb, Kb, Vb, ctab, stab);
    }
    // 3. MFMA sliding-window attention -> bf16
    {
        dim3 grid(SEQ / QTILE, NHEADS, BATCH);
        attn_mfma<<<grid, 256, 0, stream>>>(Qb, Kb, Vb, Abf);
    }
    // 4. Output projection + bias (fp32 out); 64x64 tiles
    {
        dim3 grid(DMODEL / 64, ROWS / 64, 1);
        gemm_out_bf<<<grid, 256, 0, stream>>>(Abf, Wbf + 3ull * DMODEL * DMODEL, bo, out);
    }
}